// Round 7
// baseline (3992.229 us; speedup 1.0000x reference)
//
#include <hip/hip_runtime.h>
#include <math.h>

#define NTOK 4096
#define HDIM 1024
#define NHEADS 16
#define HD 64
#define SEQ 2048
#define WSZ (HDIM*HDIM)
#define NM (NTOK*HDIM)
#define SQ7F 2.6457513110645906f   // float32(math.sqrt(7.0))
#define KC_BLK 384                 // OpenBLAS sgemm KC (k-panel) size

// Workspace (floats): wm4[0..3] | M (4*WSZ) | XD (NM, later ctx) | Q (NM, later cqm) | K | V

__device__ __forceinline__ float lane_bcast_f(float v, int l) {
  return __builtin_bit_cast(float, __builtin_amdgcn_readlane(__builtin_bit_cast(int, v), l));
}

// numpy pairwise_sum base case, n=128: 8 accumulators, ((r0+r1)+(r2+r3))+((r4+r5)+(r6+r7))
__device__ __forceinline__ float np_block128_abs(const float* a) {
  float r[8];
#pragma unroll
  for (int j = 0; j < 8; j++) r[j] = fabsf(a[j]);
  for (int i = 8; i < 128; i += 8)
#pragma unroll
    for (int j = 0; j < 8; j++) r[j] = __fadd_rn(r[j], fabsf(a[i + j]));
  return __fadd_rn(__fadd_rn(__fadd_rn(r[0], r[1]), __fadd_rn(r[2], r[3])),
                   __fadd_rn(__fadd_rn(r[4], r[5]), __fadd_rn(r[6], r[7])));
}
__device__ __forceinline__ float np_block128(const float* a) {
  float r[8];
#pragma unroll
  for (int j = 0; j < 8; j++) r[j] = a[j];
  for (int i = 8; i < 128; i += 8)
#pragma unroll
    for (int j = 0; j < 8; j++) r[j] = __fadd_rn(r[j], a[i + j]);
  return __fadd_rn(__fadd_rn(__fadd_rn(r[0], r[1]), __fadd_rn(r[2], r[3])),
                   __fadd_rn(__fadd_rn(r[4], r[5]), __fadd_rn(r[6], r[7])));
}

// ---- w_mean = np.mean(|W|) over 1M, exact numpy pairwise tree ----
__global__ __launch_bounds__(1024) void k_wmean_np(const float* __restrict__ Wq,
                                                   const float* __restrict__ Wk,
                                                   const float* __restrict__ Wv,
                                                   const float* __restrict__ Wo,
                                                   float* __restrict__ wm4) {
  __shared__ float bsA[8192];
  __shared__ float bsB[4096];
  int w = blockIdx.x, t = threadIdx.x;
  const float* W = (w == 0) ? Wq : (w == 1) ? Wk : (w == 2) ? Wv : Wo;
  for (int r = 0; r < 8; r++) {
    int blk = t * 8 + r;
    bsA[blk] = np_block128_abs(W + blk * 128);
  }
  __syncthreads();
  float* cur = bsA;
  float* nxt = bsB;
  for (int len = 4096; len >= 1; len >>= 1) {
    for (int i = t; i < len; i += 1024)
      nxt[i] = __fadd_rn(cur[2 * i], cur[2 * i + 1]);
    __syncthreads();
    float* tmp = cur; cur = nxt; nxt = tmp;
  }
  if (t == 0) wm4[w] = cur[0] / 1048576.0f;   // exact /2^20
}

// ---- M = fl(fl(round-clip(W/(wm+1e-5)) * wm) * s) ----
__global__ void k_wquant_np(const float* __restrict__ Wq, const float* __restrict__ Wk,
                            const float* __restrict__ Wv, const float* __restrict__ Wo,
                            const float* __restrict__ wm4, float* __restrict__ M,
                            const float* __restrict__ sq, const float* __restrict__ sk,
                            const float* __restrict__ sv, const float* __restrict__ so) {
  int w = blockIdx.y;
  const float* W = (w == 0) ? Wq : (w == 1) ? Wk : (w == 2) ? Wv : Wo;
  float s = (w == 0) ? sq[0] : (w == 1) ? sk[0] : (w == 2) ? sv[0] : so[0];
  float wm = wm4[w];
  float wme = __fadd_rn(wm, 1e-5f);
  int i = blockIdx.x * 1024 + threadIdx.x * 4;
  float4 v = *(const float4*)(W + i);
  float4 o;
  o.x = __fmul_rn(__fmul_rn(fminf(fmaxf(rintf(__fdiv_rn(v.x, wme)), -1.f), 1.f), wm), s);
  o.y = __fmul_rn(__fmul_rn(fminf(fmaxf(rintf(__fdiv_rn(v.y, wme)), -1.f), 1.f), wm), s);
  o.z = __fmul_rn(__fmul_rn(fminf(fmaxf(rintf(__fdiv_rn(v.z, wme)), -1.f), 1.f), wm), s);
  o.w = __fmul_rn(__fmul_rn(fminf(fmaxf(rintf(__fdiv_rn(v.w, wme)), -1.f), 1.f), wm), s);
  *(float4*)(M + (size_t)w * WSZ + i) = o;
}

// ---- int4 quant: beta = np.mean(|row|) pairwise; xd = dequant, f32 np op order ----
__global__ __launch_bounds__(256) void k_xquant_np(const float* __restrict__ x,
                                                   float* __restrict__ xd) {
  int n = blockIdx.x * 256 + threadIdx.x;
  const float* row = x + (size_t)n * HDIM;
  float bs[8];
#pragma unroll
  for (int b = 0; b < 8; b++) bs[b] = np_block128_abs(row + b * 128);
  float total = __fadd_rn(__fadd_rn(__fadd_rn(bs[0], bs[1]), __fadd_rn(bs[2], bs[3])),
                          __fadd_rn(__fadd_rn(bs[4], bs[5]), __fadd_rn(bs[6], bs[7])));
  float beta = total / 1024.0f;
  float bpe = __fadd_rn(beta, 1e-5f);
  float scale = __fmul_rn(beta, SQ7F);
  float* od = xd + (size_t)n * HDIM;
  for (int i = 0; i < 1024; i++) {
    float q = fminf(fmaxf(rintf(__fdiv_rn(__fmul_rn(row[i], SQ7F), bpe)), -8.f), 7.f);
    od[i] = __fdiv_rn(__fmul_rn(q, scale), SQ7F);
  }
}

// ---- GEMM replicating BLAS sgemm accumulation (KC=384 sequential fma chains) ----
__global__ __launch_bounds__(256) void k_gemm_blas(const float* __restrict__ A,
                                                   const float* __restrict__ Bm,
                                                   float* __restrict__ C) {
  __shared__ __align__(16) float As[16 * 68];
  __shared__ __align__(16) float Bs[16 * 68];
  int t = threadIdx.x;
  int o0 = blockIdx.x * 64, n0 = blockIdx.y * 64;
  int lr = t >> 2, lc = (t & 3) * 4;
  const float* Ag = A + (size_t)(n0 + lr) * HDIM + lc;
  const float* Bg = Bm + (size_t)(o0 + lr) * HDIM + lc;
  int tn = (t & 15) * 4, to = (t >> 4) * 4;
  float acc[4][4] = {};    // current KC-block accumulator (sequential fma chain)
  float accP[4][4] = {};   // sum of completed blocks (left-assoc adds)
  for (int kt = 0; kt < HDIM; kt += 16) {
    if (kt == KC_BLK || kt == 2 * KC_BLK) {
#pragma unroll
      for (int i = 0; i < 4; i++)
#pragma unroll
        for (int j = 0; j < 4; j++) {
          accP[i][j] = __fadd_rn(accP[i][j], acc[i][j]);
          acc[i][j] = 0.f;
        }
    }
    float4 a = *(const float4*)(Ag + kt);
    float4 b = *(const float4*)(Bg + kt);
    __syncthreads();
    float av[4] = {a.x, a.y, a.z, a.w};
    float bv[4] = {b.x, b.y, b.z, b.w};
#pragma unroll
    for (int u = 0; u < 4; u++) {
      As[(lc + u) * 68 + lr] = av[u];
      Bs[(lc + u) * 68 + lr] = bv[u];
    }
    __syncthreads();
#pragma unroll
    for (int kc = 0; kc < 16; kc++) {
      float4 a4 = *(const float4*)&As[kc * 68 + tn];
      float4 b4 = *(const float4*)&Bs[kc * 68 + to];
      float aa[4] = {a4.x, a4.y, a4.z, a4.w};
      float bb[4] = {b4.x, b4.y, b4.z, b4.w};
#pragma unroll
      for (int i = 0; i < 4; i++)
#pragma unroll
        for (int j = 0; j < 4; j++)
          acc[i][j] = __fmaf_rn(aa[i], bb[j], acc[i][j]);
    }
  }
#pragma unroll
  for (int i = 0; i < 4; i++) {
    float4 v;
    v.x = __fadd_rn(accP[i][0], acc[i][0]);
    v.y = __fadd_rn(accP[i][1], acc[i][1]);
    v.z = __fadd_rn(accP[i][2], acc[i][2]);
    v.w = __fadd_rn(accP[i][3], acc[i][3]);
    *(float4*)(C + (size_t)(n0 + tn + i) * HDIM + o0 + to) = v;
  }
}

// ---- attention v2: identical FP ops to R6, restructured data movement ----
// wave = 2 rows; block = 2 waves (4 rows); K/V staged [j][d] pad-68 (b128 aligned:
// byte stride 272 = 16*17); K frags read as b128; q/p as b128 LDS broadcasts.
__global__ __launch_bounds__(128) void k_attn_v2(const float* __restrict__ qb,
                                                 const float* __restrict__ kb,
                                                 const float* __restrict__ vb,
                                                 float* __restrict__ ctx) {
  __shared__ __align__(16) float KV[64 * 68];     // [j][d] pad 68 (17.4 KB)
  __shared__ __align__(16) float erow[4][2048];   // 32 KB, one row per wave-row
  __shared__ __align__(16) float qs[4][64];       // 1 KB
  int t = threadIdx.x, wave = t >> 6, lane = t & 63;
  int bh = blockIdx.y, b = bh >> 4, h = bh & 15;
  size_t base = (size_t)b * SEQ * HDIM + h * HD;
  int r0 = blockIdx.x * 4 + wave * 2;             // this wave's two rows
  qs[wave * 2 + 0][lane] = qb[base + (size_t)(r0 + 0) * HDIM + lane];
  qs[wave * 2 + 1][lane] = qb[base + (size_t)(r0 + 1) * HDIM + lane];
  int sj = t >> 1, shalf = t & 1;                 // staging: key row j, d-half

  // ---- Phase 1: scores (einsum SSE 4-acc chain, identical to R6) ----
  for (int c = 0; c < 32; c++) {
    __syncthreads();
    const float* kg = kb + base + (size_t)(c * 64 + sj) * HDIM + shalf * 32;
    float* dst = &KV[sj * 68 + shalf * 32];
#pragma unroll
    for (int u = 0; u < 8; u++)
      *(float4*)(dst + u * 4) = *(const float4*)(kg + u * 4);
    __syncthreads();
    float c40[4] = {0.f, 0.f, 0.f, 0.f};
    float c41[4] = {0.f, 0.f, 0.f, 0.f};
    const float* krow = &KV[lane * 68];
    const float* q0p = &qs[wave * 2 + 0][0];
    const float* q1p = &qs[wave * 2 + 1][0];
#pragma unroll
    for (int g = 0; g < 16; g++) {
      float4 k4 = *(const float4*)(krow + g * 4);
      float4 qa = *(const float4*)(q0p + g * 4);   // broadcast
      float4 qc = *(const float4*)(q1p + g * 4);   // broadcast
      c40[0] = __fadd_rn(c40[0], __fmul_rn(qa.x, k4.x));
      c40[1] = __fadd_rn(c40[1], __fmul_rn(qa.y, k4.y));
      c40[2] = __fadd_rn(c40[2], __fmul_rn(qa.z, k4.z));
      c40[3] = __fadd_rn(c40[3], __fmul_rn(qa.w, k4.w));
      c41[0] = __fadd_rn(c41[0], __fmul_rn(qc.x, k4.x));
      c41[1] = __fadd_rn(c41[1], __fmul_rn(qc.y, k4.y));
      c41[2] = __fadd_rn(c41[2], __fmul_rn(qc.z, k4.z));
      c41[3] = __fadd_rn(c41[3], __fmul_rn(qc.w, k4.w));
    }
    float sr0 = __fadd_rn(__fadd_rn(c40[0], c40[2]), __fadd_rn(c40[1], c40[3]));
    float sr1 = __fadd_rn(__fadd_rn(c41[0], c41[2]), __fadd_rn(c41[1], c41[3]));
    erow[wave * 2 + 0][c * 64 + lane] = __fmul_rn(sr0, 0.125f);
    erow[wave * 2 + 1][c * 64 + lane] = __fmul_rn(sr1, 0.125f);
  }

  // ---- softmax per wave-row (identical ops to R6; wave-private, no barrier) ----
#pragma unroll
  for (int rr = 0; rr < 2; rr++) {
    float* er = erow[wave * 2 + rr];
    float m = -INFINITY;
    for (int i = 0; i < 32; i++) m = fmaxf(m, er[lane + 64 * i]);
#pragma unroll
    for (int off = 32; off; off >>= 1) m = fmaxf(m, __shfl_xor(m, off));
    for (int i = 0; i < 32; i++) {
      int idx = lane + 64 * i;
      er[idx] = (float)exp((double)__fadd_rn(er[idx], -m));
    }
    int L = lane & 15;
    float bsum = np_block128(er + 128 * L);
    float b16[16];
#pragma unroll
    for (int j = 0; j < 16; j++) b16[j] = lane_bcast_f(bsum, j);
    float la = __fadd_rn(__fadd_rn(b16[0], b16[1]), __fadd_rn(b16[2], b16[3]));
    float lb = __fadd_rn(__fadd_rn(b16[4], b16[5]), __fadd_rn(b16[6], b16[7]));
    float lc2 = __fadd_rn(__fadd_rn(b16[8], b16[9]), __fadd_rn(b16[10], b16[11]));
    float ld = __fadd_rn(__fadd_rn(b16[12], b16[13]), __fadd_rn(b16[14], b16[15]));
    float S = __fadd_rn(__fadd_rn(la, lb), __fadd_rn(lc2, ld));
    for (int i = 0; i < 32; i++) {
      int idx = lane + 64 * i;
      er[idx] = __fdiv_rn(er[idx], S);
    }
  }

  // ---- Phase 2: PV, strictly sequential j per row (identical chain to R6) ----
  float o0 = 0.f, o1 = 0.f;
  for (int c = 0; c < 32; c++) {
    __syncthreads();
    const float* vg = vb + base + (size_t)(c * 64 + sj) * HDIM + shalf * 32;
    float* dst = &KV[sj * 68 + shalf * 32];
#pragma unroll
    for (int u = 0; u < 8; u++)
      *(float4*)(dst + u * 4) = *(const float4*)(vg + u * 4);
    __syncthreads();
    const float* er0 = &erow[wave * 2 + 0][c * 64];
    const float* er1 = &erow[wave * 2 + 1][c * 64];
#pragma unroll
    for (int u = 0; u < 16; u++) {
      float4 p0 = *(const float4*)(er0 + u * 4);   // broadcast
      float4 p1 = *(const float4*)(er1 + u * 4);   // broadcast
      float v0 = KV[(4 * u + 0) * 68 + lane];
      float v1 = KV[(4 * u + 1) * 68 + lane];
      float v2 = KV[(4 * u + 2) * 68 + lane];
      float v3 = KV[(4 * u + 3) * 68 + lane];
      o0 = __fadd_rn(o0, __fmul_rn(p0.x, v0));
      o0 = __fadd_rn(o0, __fmul_rn(p0.y, v1));
      o0 = __fadd_rn(o0, __fmul_rn(p0.z, v2));
      o0 = __fadd_rn(o0, __fmul_rn(p0.w, v3));
      o1 = __fadd_rn(o1, __fmul_rn(p1.x, v0));
      o1 = __fadd_rn(o1, __fmul_rn(p1.y, v1));
      o1 = __fadd_rn(o1, __fmul_rn(p1.z, v2));
      o1 = __fadd_rn(o1, __fmul_rn(p1.w, v3));
    }
  }
  ctx[base + (size_t)(r0 + 0) * HDIM + lane] = o0;
  ctx[base + (size_t)(r0 + 1) * HDIM + lane] = o1;
}

// ---- int8 quant + topk: f32 np-order decisions, integer-level histogram ----
__global__ __launch_bounds__(256) void k_ctxq_np(const float* __restrict__ ctx,
                                                 float* __restrict__ cqm) {
  int n = blockIdx.x, t = threadIdx.x;
  __shared__ float red[256];
  __shared__ int hist[129];
  __shared__ int tsh;
  float4 cv = *(const float4*)(ctx + (size_t)n * HDIM + t * 4);
  float mx = fmaxf(fmaxf(fabsf(cv.x), fabsf(cv.y)), fmaxf(fabsf(cv.z), fabsf(cv.w)));
  red[t] = mx; __syncthreads();
  for (int st = 128; st > 0; st >>= 1) {
    if (t < st) red[t] = fmaxf(red[t], red[t + st]);
    __syncthreads();
  }
  float gamma = red[0];
  if (t < 129) hist[t] = 0;
  __syncthreads();
  float gpe = __fadd_rn(gamma, 1e-5f);
  float q0 = fminf(fmaxf(rintf(__fdiv_rn(__fmul_rn(cv.x, 127.0f), gpe)), -128.f), 127.f);
  float q1 = fminf(fmaxf(rintf(__fdiv_rn(__fmul_rn(cv.y, 127.0f), gpe)), -128.f), 127.f);
  float q2 = fminf(fmaxf(rintf(__fdiv_rn(__fmul_rn(cv.z, 127.0f), gpe)), -128.f), 127.f);
  float q3 = fminf(fmaxf(rintf(__fdiv_rn(__fmul_rn(cv.w, 127.0f), gpe)), -128.f), 127.f);
  int a0 = (int)fabsf(q0), a1 = (int)fabsf(q1), a2 = (int)fabsf(q2), a3 = (int)fabsf(q3);
  atomicAdd(&hist[a0], 1); atomicAdd(&hist[a1], 1);
  atomicAdd(&hist[a2], 1); atomicAdd(&hist[a3], 1);
  __syncthreads();
  if (t < 129) {
    int cum = 0;
    for (int u = 0; u <= t; u++) cum += hist[u];
    if (cum >= 512 && cum - hist[t] < 512) tsh = t;
  }
  __syncthreads();
  int thr = tsh;
  float4 o;
  o.x = (a0 >= thr) ? __fdiv_rn(__fmul_rn(q0, gamma), 127.0f) : 0.f;
  o.y = (a1 >= thr) ? __fdiv_rn(__fmul_rn(q1, gamma), 127.0f) : 0.f;
  o.z = (a2 >= thr) ? __fdiv_rn(__fmul_rn(q2, gamma), 127.0f) : 0.f;
  o.w = (a3 >= thr) ? __fdiv_rn(__fmul_rn(q3, gamma), 127.0f) : 0.f;
  *(float4*)(cqm + (size_t)n * HDIM + t * 4) = o;
}

extern "C" void kernel_launch(void* const* d_in, const int* in_sizes, int n_in,
                              void* d_out, int out_size, void* d_ws, size_t ws_size,
                              hipStream_t stream) {
  const float* x  = (const float*)d_in[0];
  const float* Wq = (const float*)d_in[1];
  const float* Wk = (const float*)d_in[2];
  const float* Wv = (const float*)d_in[3];
  const float* Wo = (const float*)d_in[4];
  const float* sq = (const float*)d_in[5];
  const float* sk = (const float*)d_in[6];
  const float* sv = (const float*)d_in[7];
  const float* so = (const float*)d_in[8];
  float* out = (float*)d_out;

  float* F   = (float*)d_ws;
  float* wm4 = F;
  float* M   = F + 1024;
  float* XD  = M + (size_t)4 * WSZ;
  float* Q   = XD + (size_t)NM;
  float* K   = Q + (size_t)NM;
  float* V   = K + (size_t)NM;
  float* ctx = XD;
  float* cqm = Q;

  k_wmean_np<<<4, 1024, 0, stream>>>(Wq, Wk, Wv, Wo, wm4);
  k_wquant_np<<<dim3(1024, 4), 256, 0, stream>>>(Wq, Wk, Wv, Wo, wm4, M, sq, sk, sv, so);
  k_xquant_np<<<16, 256, 0, stream>>>(x, XD);

  k_gemm_blas<<<dim3(16, 64), 256, 0, stream>>>(XD, M + 0 * (size_t)WSZ, Q);
  k_gemm_blas<<<dim3(16, 64), 256, 0, stream>>>(XD, M + 1 * (size_t)WSZ, K);
  k_gemm_blas<<<dim3(16, 64), 256, 0, stream>>>(XD, M + 2 * (size_t)WSZ, V);

  k_attn_v2<<<dim3(512, 32), 128, 0, stream>>>(Q, K, V, ctx);

  k_ctxq_np<<<4096, 256, 0, stream>>>(ctx, cqm);

  k_gemm_blas<<<dim3(16, 64), 256, 0, stream>>>(cqm, M + 3 * (size_t)WSZ, out);
}

// Round 8
// 2945.561 us; speedup vs baseline: 1.3553x; 1.3553x over previous
//
#include <hip/hip_runtime.h>
#include <math.h>

#define NTOK 4096
#define HDIM 1024
#define NHEADS 16
#define HD 64
#define SEQ 2048
#define WSZ (HDIM*HDIM)
#define NM (NTOK*HDIM)
#define SQ7F 2.6457513110645906f   // float32(math.sqrt(7.0))
#define KC_BLK 384                 // OpenBLAS sgemm KC (k-panel) size

// Workspace (floats): wm4[0..3] | M (4*WSZ) | XD (NM, later ctx) | Q (NM, later cqm) | K | V

__device__ __forceinline__ float lane_bcast_f(float v, int l) {
  return __builtin_bit_cast(float, __builtin_amdgcn_readlane(__builtin_bit_cast(int, v), l));
}

// numpy pairwise_sum base case, n=128: 8 accumulators, ((r0+r1)+(r2+r3))+((r4+r5)+(r6+r7))
__device__ __forceinline__ float np_block128_abs(const float* a) {
  float r[8];
#pragma unroll
  for (int j = 0; j < 8; j++) r[j] = fabsf(a[j]);
  for (int i = 8; i < 128; i += 8)
#pragma unroll
    for (int j = 0; j < 8; j++) r[j] = __fadd_rn(r[j], fabsf(a[i + j]));
  return __fadd_rn(__fadd_rn(__fadd_rn(r[0], r[1]), __fadd_rn(r[2], r[3])),
                   __fadd_rn(__fadd_rn(r[4], r[5]), __fadd_rn(r[6], r[7])));
}
__device__ __forceinline__ float np_block128(const float* a) {
  float r[8];
#pragma unroll
  for (int j = 0; j < 8; j++) r[j] = a[j];
  for (int i = 8; i < 128; i += 8)
#pragma unroll
    for (int j = 0; j < 8; j++) r[j] = __fadd_rn(r[j], a[i + j]);
  return __fadd_rn(__fadd_rn(__fadd_rn(r[0], r[1]), __fadd_rn(r[2], r[3])),
                   __fadd_rn(__fadd_rn(r[4], r[5]), __fadd_rn(r[6], r[7])));
}

// ---- w_mean = np.mean(|W|) over 1M, exact numpy pairwise tree ----
__global__ __launch_bounds__(1024) void k_wmean_np(const float* __restrict__ Wq,
                                                   const float* __restrict__ Wk,
                                                   const float* __restrict__ Wv,
                                                   const float* __restrict__ Wo,
                                                   float* __restrict__ wm4) {
  __shared__ float bsA[8192];
  __shared__ float bsB[4096];
  int w = blockIdx.x, t = threadIdx.x;
  const float* W = (w == 0) ? Wq : (w == 1) ? Wk : (w == 2) ? Wv : Wo;
  for (int r = 0; r < 8; r++) {
    int blk = t * 8 + r;
    bsA[blk] = np_block128_abs(W + blk * 128);
  }
  __syncthreads();
  float* cur = bsA;
  float* nxt = bsB;
  for (int len = 4096; len >= 1; len >>= 1) {
    for (int i = t; i < len; i += 1024)
      nxt[i] = __fadd_rn(cur[2 * i], cur[2 * i + 1]);
    __syncthreads();
    float* tmp = cur; cur = nxt; nxt = tmp;
  }
  if (t == 0) wm4[w] = cur[0] / 1048576.0f;   // exact /2^20
}

// ---- M = fl(fl(round-clip(W/(wm+1e-5)) * wm) * s) ----
__global__ void k_wquant_np(const float* __restrict__ Wq, const float* __restrict__ Wk,
                            const float* __restrict__ Wv, const float* __restrict__ Wo,
                            const float* __restrict__ wm4, float* __restrict__ M,
                            const float* __restrict__ sq, const float* __restrict__ sk,
                            const float* __restrict__ sv, const float* __restrict__ so) {
  int w = blockIdx.y;
  const float* W = (w == 0) ? Wq : (w == 1) ? Wk : (w == 2) ? Wv : Wo;
  float s = (w == 0) ? sq[0] : (w == 1) ? sk[0] : (w == 2) ? sv[0] : so[0];
  float wm = wm4[w];
  float wme = __fadd_rn(wm, 1e-5f);
  int i = blockIdx.x * 1024 + threadIdx.x * 4;
  float4 v = *(const float4*)(W + i);
  float4 o;
  o.x = __fmul_rn(__fmul_rn(fminf(fmaxf(rintf(__fdiv_rn(v.x, wme)), -1.f), 1.f), wm), s);
  o.y = __fmul_rn(__fmul_rn(fminf(fmaxf(rintf(__fdiv_rn(v.y, wme)), -1.f), 1.f), wm), s);
  o.z = __fmul_rn(__fmul_rn(fminf(fmaxf(rintf(__fdiv_rn(v.z, wme)), -1.f), 1.f), wm), s);
  o.w = __fmul_rn(__fmul_rn(fminf(fmaxf(rintf(__fdiv_rn(v.w, wme)), -1.f), 1.f), wm), s);
  *(float4*)(M + (size_t)w * WSZ + i) = o;
}

// ---- int4 quant: beta = np.mean(|row|) pairwise; xd = dequant, f32 np op order ----
__global__ __launch_bounds__(64) void k_xquant_np(const float* __restrict__ x,
                                                  float* __restrict__ xd) {
  int n = blockIdx.x * 64 + threadIdx.x;
  const float* row = x + (size_t)n * HDIM;
  float bs[8];
#pragma unroll
  for (int b = 0; b < 8; b++) bs[b] = np_block128_abs(row + b * 128);
  float total = __fadd_rn(__fadd_rn(__fadd_rn(bs[0], bs[1]), __fadd_rn(bs[2], bs[3])),
                          __fadd_rn(__fadd_rn(bs[4], bs[5]), __fadd_rn(bs[6], bs[7])));
  float beta = total / 1024.0f;
  float bpe = __fadd_rn(beta, 1e-5f);
  float scale = __fmul_rn(beta, SQ7F);
  float* od = xd + (size_t)n * HDIM;
  for (int i = 0; i < 1024; i++) {
    float q = fminf(fmaxf(rintf(__fdiv_rn(__fmul_rn(row[i], SQ7F), bpe)), -8.f), 7.f);
    od[i] = __fdiv_rn(__fmul_rn(q, scale), SQ7F);
  }
}

// ---- GEMM replicating BLAS sgemm accumulation (KC=384 sequential fma chains) ----
__global__ __launch_bounds__(256) void k_gemm_blas(const float* __restrict__ A,
                                                   const float* __restrict__ Bm,
                                                   float* __restrict__ C) {
  __shared__ __align__(16) float As[16 * 68];
  __shared__ __align__(16) float Bs[16 * 68];
  int t = threadIdx.x;
  int o0 = blockIdx.x * 64, n0 = blockIdx.y * 64;
  int lr = t >> 2, lc = (t & 3) * 4;
  const float* Ag = A + (size_t)(n0 + lr) * HDIM + lc;
  const float* Bg = Bm + (size_t)(o0 + lr) * HDIM + lc;
  int tn = (t & 15) * 4, to = (t >> 4) * 4;
  float acc[4][4] = {};    // current KC-block accumulator (sequential fma chain)
  float accP[4][4] = {};   // sum of completed blocks (left-assoc adds)
  for (int kt = 0; kt < HDIM; kt += 16) {
    if (kt == KC_BLK || kt == 2 * KC_BLK) {
#pragma unroll
      for (int i = 0; i < 4; i++)
#pragma unroll
        for (int j = 0; j < 4; j++) {
          accP[i][j] = __fadd_rn(accP[i][j], acc[i][j]);
          acc[i][j] = 0.f;
        }
    }
    float4 a = *(const float4*)(Ag + kt);
    float4 b = *(const float4*)(Bg + kt);
    __syncthreads();
    float av[4] = {a.x, a.y, a.z, a.w};
    float bv[4] = {b.x, b.y, b.z, b.w};
#pragma unroll
    for (int u = 0; u < 4; u++) {
      As[(lc + u) * 68 + lr] = av[u];
      Bs[(lc + u) * 68 + lr] = bv[u];
    }
    __syncthreads();
#pragma unroll
    for (int kc = 0; kc < 16; kc++) {
      float4 a4 = *(const float4*)&As[kc * 68 + tn];
      float4 b4 = *(const float4*)&Bs[kc * 68 + to];
      float aa[4] = {a4.x, a4.y, a4.z, a4.w};
      float bb[4] = {b4.x, b4.y, b4.z, b4.w};
#pragma unroll
      for (int i = 0; i < 4; i++)
#pragma unroll
        for (int j = 0; j < 4; j++)
          acc[i][j] = __fmaf_rn(aa[i], bb[j], acc[i][j]);
    }
  }
#pragma unroll
  for (int i = 0; i < 4; i++) {
    float4 v;
    v.x = __fadd_rn(accP[i][0], acc[i][0]);
    v.y = __fadd_rn(accP[i][1], acc[i][1]);
    v.z = __fadd_rn(accP[i][2], acc[i][2]);
    v.w = __fadd_rn(accP[i][3], acc[i][3]);
    *(float4*)(C + (size_t)(n0 + tn + i) * HDIM + o0 + to) = v;
  }
}

// ---- attention: R6 structure, erow stored with 129-stride block padding ----
// padded index = idx + idx/128 -> np_block128 streams hit 16 distinct banks.
// All FP ops and accumulation chains bit-identical to R6.
__global__ __launch_bounds__(256) void k_attn_np(const float* __restrict__ qb,
                                                 const float* __restrict__ kb,
                                                 const float* __restrict__ vb,
                                                 float* __restrict__ ctx) {
  __shared__ float Ks[64 * 65];        // [d][j] ints, stride 65 (conflict-free)
  __shared__ float ebuf[4 * 2064];     // per-wave padded score row (16 x 129)
  int bh = blockIdx.y;
  int b = bh >> 4, h = bh & 15;
  int t = threadIdx.x, wave = t >> 6, lane = t & 63;
  int row = blockIdx.x * 4 + wave;
  size_t base = (size_t)b * SEQ * HDIM + h * HD;
  float qreg = qb[base + (size_t)row * HDIM + lane];   // lane = d
  float* erow = ebuf + wave * 2064;
  int sj = t >> 2, part = t & 3;

  // Phase 1: scores
  for (int c = 0; c < 32; c++) {
    int j0 = c * 64;
    __syncthreads();
    const float* kg = kb + base + (size_t)(j0 + sj) * HDIM + part * 16;
#pragma unroll
    for (int u = 0; u < 4; u++) {
      float4 kv = *(const float4*)(kg + u * 4);
      int d0 = part * 16 + u * 4;
      Ks[(d0 + 0) * 65 + sj] = kv.x; Ks[(d0 + 1) * 65 + sj] = kv.y;
      Ks[(d0 + 2) * 65 + sj] = kv.z; Ks[(d0 + 3) * 65 + sj] = kv.w;
    }
    __syncthreads();
    float c4[4] = {0.f, 0.f, 0.f, 0.f};
#pragma unroll
    for (int i = 0; i < 16; i++) {
#pragma unroll
      for (int jj = 0; jj < 4; jj++) {
        int d = 4 * i + jj;
        c4[jj] = __fadd_rn(c4[jj], __fmul_rn(lane_bcast_f(qreg, d), Ks[d * 65 + lane]));
      }
    }
    float sr = __fadd_rn(__fadd_rn(c4[0], c4[2]), __fadd_rn(c4[1], c4[3]));
    erow[j0 + (c >> 1) + lane] = sr * 0.125f;   // padded store
  }

  float m = -INFINITY;
  for (int i = 0; i < 32; i++) m = fmaxf(m, erow[lane + 64 * i + (i >> 1)]);
#pragma unroll
  for (int off = 32; off; off >>= 1) m = fmaxf(m, __shfl_xor(m, off));
  for (int i = 0; i < 32; i++) {
    int idx = lane + 64 * i + (i >> 1);
    erow[idx] = (float)exp((double)__fadd_rn(erow[idx], -m));
  }
  int L = lane & 15;
  float bsum = np_block128(erow + 129 * L);    // 16 streams, 16 distinct banks
  float b16[16];
#pragma unroll
  for (int j = 0; j < 16; j++) b16[j] = lane_bcast_f(bsum, j);
  float la = __fadd_rn(__fadd_rn(b16[0], b16[1]), __fadd_rn(b16[2], b16[3]));
  float lb = __fadd_rn(__fadd_rn(b16[4], b16[5]), __fadd_rn(b16[6], b16[7]));
  float lc2 = __fadd_rn(__fadd_rn(b16[8], b16[9]), __fadd_rn(b16[10], b16[11]));
  float ld = __fadd_rn(__fadd_rn(b16[12], b16[13]), __fadd_rn(b16[14], b16[15]));
  float S = __fadd_rn(__fadd_rn(la, lb), __fadd_rn(lc2, ld));
  for (int i = 0; i < 32; i++) {
    int idx = lane + 64 * i + (i >> 1);
    erow[idx] = __fdiv_rn(erow[idx], S);
  }

  // Phase 2: ctx[d] = sequential sum over k of p[k]*v[k,d]
  float o = 0.f;
  for (int c = 0; c < 32; c++) {
    int j0 = c * 64;
    __syncthreads();
    const float* vg = vb + base + (size_t)(j0 + sj) * HDIM + part * 16;
#pragma unroll
    for (int u = 0; u < 4; u++) {
      float4 vv = *(const float4*)(vg + u * 4);
      int d0 = part * 16 + u * 4;
      Ks[(d0 + 0) * 65 + sj] = vv.x; Ks[(d0 + 1) * 65 + sj] = vv.y;
      Ks[(d0 + 2) * 65 + sj] = vv.z; Ks[(d0 + 3) * 65 + sj] = vv.w;
    }
    __syncthreads();
    const float* erc = erow + j0 + (c >> 1);   // padded base (uniform per chunk)
#pragma unroll 8
    for (int j = 0; j < 64; j++) {
      o = __fadd_rn(o, __fmul_rn(erc[j], Ks[lane * 65 + j]));
    }
  }
  ctx[base + (size_t)row * HDIM + lane] = o;
}

// ---- int8 quant + topk: f32 np-order decisions, integer-level histogram ----
__global__ __launch_bounds__(256) void k_ctxq_np(const float* __restrict__ ctx,
                                                 float* __restrict__ cqm) {
  int n = blockIdx.x, t = threadIdx.x;
  __shared__ float red[256];
  __shared__ int hist[129];
  __shared__ int tsh;
  float4 cv = *(const float4*)(ctx + (size_t)n * HDIM + t * 4);
  float mx = fmaxf(fmaxf(fabsf(cv.x), fabsf(cv.y)), fmaxf(fabsf(cv.z), fabsf(cv.w)));
  red[t] = mx; __syncthreads();
  for (int st = 128; st > 0; st >>= 1) {
    if (t < st) red[t] = fmaxf(red[t], red[t + st]);
    __syncthreads();
  }
  float gamma = red[0];
  if (t < 129) hist[t] = 0;
  __syncthreads();
  float gpe = __fadd_rn(gamma, 1e-5f);
  float q0 = fminf(fmaxf(rintf(__fdiv_rn(__fmul_rn(cv.x, 127.0f), gpe)), -128.f), 127.f);
  float q1 = fminf(fmaxf(rintf(__fdiv_rn(__fmul_rn(cv.y, 127.0f), gpe)), -128.f), 127.f);
  float q2 = fminf(fmaxf(rintf(__fdiv_rn(__fmul_rn(cv.z, 127.0f), gpe)), -128.f), 127.f);
  float q3 = fminf(fmaxf(rintf(__fdiv_rn(__fmul_rn(cv.w, 127.0f), gpe)), -128.f), 127.f);
  int a0 = (int)fabsf(q0), a1 = (int)fabsf(q1), a2 = (int)fabsf(q2), a3 = (int)fabsf(q3);
  atomicAdd(&hist[a0], 1); atomicAdd(&hist[a1], 1);
  atomicAdd(&hist[a2], 1); atomicAdd(&hist[a3], 1);
  __syncthreads();
  if (t < 129) {
    int cum = 0;
    for (int u = 0; u <= t; u++) cum += hist[u];
    if (cum >= 512 && cum - hist[t] < 512) tsh = t;
  }
  __syncthreads();
  int thr = tsh;
  float4 o;
  o.x = (a0 >= thr) ? __fdiv_rn(__fmul_rn(q0, gamma), 127.0f) : 0.f;
  o.y = (a1 >= thr) ? __fdiv_rn(__fmul_rn(q1, gamma), 127.0f) : 0.f;
  o.z = (a2 >= thr) ? __fdiv_rn(__fmul_rn(q2, gamma), 127.0f) : 0.f;
  o.w = (a3 >= thr) ? __fdiv_rn(__fmul_rn(q3, gamma), 127.0f) : 0.f;
  *(float4*)(cqm + (size_t)n * HDIM + t * 4) = o;
}

extern "C" void kernel_launch(void* const* d_in, const int* in_sizes, int n_in,
                              void* d_out, int out_size, void* d_ws, size_t ws_size,
                              hipStream_t stream) {
  const float* x  = (const float*)d_in[0];
  const float* Wq = (const float*)d_in[1];
  const float* Wk = (const float*)d_in[2];
  const float* Wv = (const float*)d_in[3];
  const float* Wo = (const float*)d_in[4];
  const float* sq = (const float*)d_in[5];
  const float* sk = (const float*)d_in[6];
  const float* sv = (const float*)d_in[7];
  const float* so = (const float*)d_in[8];
  float* out = (float*)d_out;

  float* F   = (float*)d_ws;
  float* wm4 = F;
  float* M   = F + 1024;
  float* XD  = M + (size_t)4 * WSZ;
  float* Q   = XD + (size_t)NM;
  float* K   = Q + (size_t)NM;
  float* V   = K + (size_t)NM;
  float* ctx = XD;
  float* cqm = Q;

  k_wmean_np<<<4, 1024, 0, stream>>>(Wq, Wk, Wv, Wo, wm4);
  k_wquant_np<<<dim3(1024, 4), 256, 0, stream>>>(Wq, Wk, Wv, Wo, wm4, M, sq, sk, sv, so);
  k_xquant_np<<<64, 64, 0, stream>>>(x, XD);

  k_gemm_blas<<<dim3(16, 64), 256, 0, stream>>>(XD, M + 0 * (size_t)WSZ, Q);
  k_gemm_blas<<<dim3(16, 64), 256, 0, stream>>>(XD, M + 1 * (size_t)WSZ, K);
  k_gemm_blas<<<dim3(16, 64), 256, 0, stream>>>(XD, M + 2 * (size_t)WSZ, V);

  k_attn_np<<<dim3(512, 32), 256, 0, stream>>>(Q, K, V, ctx);

  k_ctxq_np<<<4096, 256, 0, stream>>>(ctx, cqm);

  k_gemm_blas<<<dim3(16, 64), 256, 0, stream>>>(cqm, M + 3 * (size_t)WSZ, out);
}